// Round 3
// baseline (1098.108 us; speedup 1.0000x reference)
//
#include <hip/hip_runtime.h>
#include <hip/hip_bf16.h>

using bf16 = __hip_bfloat16;
using bf16x8 = __attribute__((ext_vector_type(8))) short;
using f32x4  = __attribute__((ext_vector_type(4))) float;

__device__ inline unsigned short f2bu(float f){ bf16 h = __float2bfloat16(f); return *(unsigned short*)&h; }

constexpr int D_ = 1024, L_ = 2048;

// ---------------------------------------------------------------------------
// q[e] = bq[e] + sum_d cq[d]*wq[e,d]
__global__ __launch_bounds__(256) void k_q(const float* __restrict__ cq, const float* __restrict__ wq,
                                           const float* __restrict__ bq, float* __restrict__ q){
  int e = blockIdx.x*256 + threadIdx.x;
  const float* wr = wq + (size_t)e*D_;
  float acc = bq[e];
  for (int dd=0; dd<D_; dd+=8){
    float4 a0 = *(const float4*)(wr+dd), a1 = *(const float4*)(wr+dd+4);
    float4 c0 = *(const float4*)(cq+dd), c1 = *(const float4*)(cq+dd+4);
    acc += a0.x*c0.x + a0.y*c0.y + a0.z*c0.z + a0.w*c0.w
         + a1.x*c1.x + a1.y*c1.y + a1.z*c1.z + a1.w*c1.w;
  }
  q[e] = acc;
}

// qwk[hh][d] = sum_e q[hh*64+e]*wk[hh*64+e, d]
__global__ __launch_bounds__(256) void k_qwk(const float* __restrict__ q, const float* __restrict__ wk,
                                             float* __restrict__ qwk){
  int idx = blockIdx.x*256 + threadIdx.x;
  int hh = idx >> 10, d = idx & 1023;
  float acc = 0.f;
  for (int e=0;e<64;++e)
    acc += q[hh*64+e]*wk[(size_t)(hh*64+e)*D_ + d];
  qwk[idx] = acc;
}

// qwkp[v][hh][k] = (1/8) sum_d qwk[hh][d]*proj_w[v][d][k]
// qwkc[v][hh]    = (1/8) sum_d qwk[hh][d]*(proj_b[v][d]+ce[v][d])
__global__ __launch_bounds__(256) void k_qwkpc(const float* __restrict__ qwk, const float* __restrict__ proj_w,
                                               const float* __restrict__ proj_b, const float* __restrict__ ce,
                                               float* __restrict__ qwkp, float* __restrict__ qwkc){
  int idx = blockIdx.x*256 + threadIdx.x;
  const float s = 0.125f; // 1/sqrt(64)
  if (idx < 4096){
    int v = idx>>8, hh = (idx>>4)&15, k = idx&15;
    float acc = 0.f;
    for (int d=0; d<D_; ++d)
      acc += qwk[hh*D_+d]*proj_w[((size_t)v*D_+d)*16 + k];
    qwkp[(v*16+hh)*16 + k] = acc*s;
  } else if (idx < 4352){
    int r = idx-4096; int v = r>>4, hh = r&15;
    float acc = 0.f;
    for (int d=0; d<D_; ++d)
      acc += qwk[hh*D_+d]*(proj_b[v*D_+d] + ce[v*D_+d]);
    qwkc[r] = acc*s;
  }
}

// wvp[v][d][k] = sum_dd wv[d,dd]*proj_w[v][dd][k];  wvc[v][d] = sum_dd wv[d,dd]*(pb+ce)[v][dd] + bv[d]
__global__ __launch_bounds__(256) void k_wvp(const float* __restrict__ wv, const float* __restrict__ proj_w,
                                             const float* __restrict__ proj_b, const float* __restrict__ ce,
                                             const float* __restrict__ bv, float* __restrict__ wvp,
                                             float* __restrict__ wvc){
  int idx = blockIdx.x*256 + threadIdx.x;   // v fastest for wv broadcast
  int v = idx & 15, d = idx >> 4;
  float acck[16];
  #pragma unroll
  for (int k=0;k<16;++k) acck[k] = 0.f;
  float accc = 0.f;
  const float* wr = wv + (size_t)d*D_;
  for (int dd=0; dd<D_; ++dd){
    float wvd = wr[dd];
    const float* pr = proj_w + ((size_t)v*D_ + dd)*16;
    #pragma unroll
    for (int j=0;j<4;++j){
      float4 a = *(const float4*)(pr + 4*j);
      acck[4*j+0] += wvd*a.x; acck[4*j+1] += wvd*a.y;
      acck[4*j+2] += wvd*a.z; acck[4*j+3] += wvd*a.w;
    }
    accc += wvd*(proj_b[v*D_+dd] + ce[v*D_+dd]);
  }
  float* o = wvp + ((size_t)v*D_ + d)*16;
  #pragma unroll
  for (int k=0;k<16;++k) o[k] = acck[k];
  wvc[v*D_ + d] = accc + bv[d];
}

// ---------------------------------------------------------------------------
// wvT[dd][d] = wv[d][dd]   (64x64 LDS tile transpose, fp32)
__global__ __launch_bounds__(256) void k_transpose(const float* __restrict__ in, float* __restrict__ outp){
  __shared__ float t[64][68];
  const int tid = threadIdx.x;
  const int r = tid >> 2, c0 = (tid & 3)*16;
  const int d0 = blockIdx.y*64, dd0 = blockIdx.x*64;
  #pragma unroll
  for (int j=0;j<4;++j){
    float4 v = *(const float4*)(in + (size_t)(d0+r)*D_ + dd0 + c0 + 4*j);
    t[r][c0+4*j+0] = v.x; t[r][c0+4*j+1] = v.y; t[r][c0+4*j+2] = v.z; t[r][c0+4*j+3] = v.w;
  }
  __syncthreads();
  #pragma unroll
  for (int j=0;j<4;++j){
    float4 o;
    o.x = t[c0+4*j+0][r]; o.y = t[c0+4*j+1][r]; o.z = t[c0+4*j+2][r]; o.w = t[c0+4*j+3][r];
    *(float4*)(outp + (size_t)(dd0+r)*D_ + d0 + c0 + 4*j) = o;
  }
}

// ---------------------------------------------------------------------------
// C[M][N] = A1[M][K1]*B1t[N][K1]^T + A2[M][K2]*B2t[N][K2]^T (+bias[N])
// fp32 in/out; staging converts fp32->bf16 into LDS; MFMA 16x16x32 bf16, fp32 accum.
// grid (N/128, M/128), 256 threads = 4 waves (2x2), wave tile 64x64.
__global__ __launch_bounds__(256) void k_gemm_cat(const float* __restrict__ A1, const float* __restrict__ B1,
                                                  const float* __restrict__ A2, const float* __restrict__ B2,
                                                  const float* __restrict__ bias, float* __restrict__ C,
                                                  int M, int N, int K1, int K2){
  __shared__ unsigned short As[128][40];   // bf16 bits; row stride 80B (16B-aligned)
  __shared__ unsigned short Bs[128][40];
  const int tid = threadIdx.x;
  const int wave = tid >> 6, lane = tid & 63;
  const int wm = wave & 1, wn = wave >> 1;
  const int m0 = blockIdx.y*128, n0 = blockIdx.x*128;
  const int lm = lane & 15, kg = lane >> 4;
  f32x4 acc[4][4];
  #pragma unroll
  for (int mf=0;mf<4;++mf)
    #pragma unroll
    for (int nf=0;nf<4;++nf)
      acc[mf][nf] = (f32x4){0.f,0.f,0.f,0.f};
  const int K = K1 + K2;
  for (int k0=0; k0<K; k0+=32){
    const float* Ap; const float* Bp; int kk; int KA;
    if (k0 < K1){ Ap = A1; Bp = B1; kk = k0;      KA = K1; }
    else        { Ap = A2; Bp = B2; kk = k0 - K1; KA = K2; }
    #pragma unroll
    for (int i=0;i<4;++i){
      int s = tid + 256*i;                 // 1024 float4-slots per tile
      int row = s >> 3, col = (s & 7)*4;   // 8 slots per 32-wide row
      float4 av = *(const float4*)(Ap + (size_t)(m0+row)*KA + kk + col);
      float4 bv = *(const float4*)(Bp + (size_t)(n0+row)*KA + kk + col);
      *(ushort4*)(&As[row][col]) = make_ushort4(f2bu(av.x), f2bu(av.y), f2bu(av.z), f2bu(av.w));
      *(ushort4*)(&Bs[row][col]) = make_ushort4(f2bu(bv.x), f2bu(bv.y), f2bu(bv.z), f2bu(bv.w));
    }
    __syncthreads();
    bf16x8 af[4], bfr[4];
    #pragma unroll
    for (int f=0;f<4;++f){
      af[f]  = *(const bf16x8*)(&As[wm*64 + f*16 + lm][kg*8]);
      bfr[f] = *(const bf16x8*)(&Bs[wn*64 + f*16 + lm][kg*8]);
    }
    #pragma unroll
    for (int mf=0;mf<4;++mf)
      #pragma unroll
      for (int nf=0;nf<4;++nf)
        acc[mf][nf] = __builtin_amdgcn_mfma_f32_16x16x32_bf16(af[mf], bfr[nf], acc[mf][nf], 0,0,0);
    __syncthreads();
  }
  #pragma unroll
  for (int nf=0;nf<4;++nf){
    int col = n0 + wn*64 + nf*16 + lm;
    float bval = bias ? bias[col] : 0.f;
    #pragma unroll
    for (int mf=0;mf<4;++mf){
      #pragma unroll
      for (int r=0;r<4;++r){
        int row = m0 + wm*64 + mf*16 + kg*4 + r;   // C: col=lane&15, row=(lane>>4)*4+reg
        C[(size_t)row*N + col] = acc[mf][nf][r] + bval;
      }
    }
  }
}

// ---------------------------------------------------------------------------
// fused chunk: patches -> scores -> softmax -> ctx0 (fp32, 1024 x 1024 rows per chunk)
// grid 256 = 64 site-groups (16 sites) x 4 d-chunks (256 d)
__global__ __launch_bounds__(256) void k_fused(const float* __restrict__ x, int bb, int lb,
                                               const float* __restrict__ qwkp, const float* __restrict__ qwkc,
                                               const float* __restrict__ wvp, const float* __restrict__ wvc,
                                               float* __restrict__ ctx){
  __shared__ float patchL[16][16][16];  // [s][v][k]
  __shared__ float attnL[16][16][16];   // [s][hh][v]
  const int tid = threadIdx.x;
  const int sg = blockIdx.x >> 2;
  const int dc = blockIdx.x & 3;
  { // phase A: load patches (thread = (s, v))
    const int s = tid >> 4, v = tid & 15;
    const int l = lb + sg*16 + s;
    const int hi = l >> 6, wi = l & 63;
    const float* xp = x + ((size_t)((bb*16+v)*128 + hi*4)*256 + wi*4);
    #pragma unroll
    for (int pi=0; pi<4; ++pi){
      float4 r = *(const float4*)(xp + pi*256);
      patchL[s][v][pi*4+0] = r.x; patchL[s][v][pi*4+1] = r.y;
      patchL[s][v][pi*4+2] = r.z; patchL[s][v][pi*4+3] = r.w;
    }
  }
  __syncthreads();
  { // phase B: scores + softmax (thread = (s, hh)); v-const terms cancel in softmax
    const int s = tid >> 4, hh = tid & 15;
    float sc[16];
    #pragma unroll
    for (int v=0; v<16; ++v){
      float a = qwkc[v*16+hh];
      const float* qp = qwkp + (v*16+hh)*16;
      #pragma unroll
      for (int k=0;k<16;++k) a += qp[k]*patchL[s][v][k];
      sc[v] = a;
    }
    float mx = sc[0];
    #pragma unroll
    for (int v=1;v<16;++v) mx = fmaxf(mx, sc[v]);
    float sum = 0.f;
    #pragma unroll
    for (int v=0;v<16;++v){ sc[v] = __expf(sc[v]-mx); sum += sc[v]; }
    float inv = 1.f/sum;
    #pragma unroll
    for (int v=0;v<16;++v) attnL[s][hh][v] = sc[v]*inv;
  }
  __syncthreads();
  // phase C: ctx0[s][d] = sum_v attn[s,hh,v]*(wvp[v,d,:]·patch[s,v,:] + wvc[v,d])
  const int d = dc*256 + tid;
  const int hh = d >> 6;
  const int s0 = sg*16;
  float acc[16];
  #pragma unroll
  for (int s=0;s<16;++s) acc[s] = 0.f;
  for (int v=0; v<16; ++v){
    const float* wp = wvp + ((size_t)v*D_ + d)*16;
    float w[16];
    #pragma unroll
    for (int k=0;k<16;++k) w[k] = wp[k];
    const float c0 = wvc[v*D_ + d];
    #pragma unroll
    for (int s=0;s<16;++s){
      float dot = c0;
      #pragma unroll
      for (int k=0;k<16;++k) dot += w[k]*patchL[s][v][k];
      acc[s] += attnL[s][hh][v]*dot;
    }
  }
  #pragma unroll
  for (int s=0;s<16;++s) ctx[(size_t)(s0+s)*D_ + d] = acc[s];
}

// ---------------------------------------------------------------------------
extern "C" void kernel_launch(void* const* d_in, const int* in_sizes, int n_in,
                              void* d_out, int out_size, void* d_ws, size_t ws_size,
                              hipStream_t stream){
  const float* x      = (const float*)d_in[0];
  const float* proj_w = (const float*)d_in[1];
  const float* proj_b = (const float*)d_in[2];
  const float* ce     = (const float*)d_in[3];
  const float* pe     = (const float*)d_in[4];
  const float* cq     = (const float*)d_in[5];
  const float* wq     = (const float*)d_in[6];
  const float* wk     = (const float*)d_in[7];
  const float* wv     = (const float*)d_in[8];
  const float* bq     = (const float*)d_in[9];
  // bk (d_in[10]) cancels in softmax
  const float* bv     = (const float*)d_in[11];
  const float* wo     = (const float*)d_in[12];
  const float* bo     = (const float*)d_in[13];
  float* out = (float*)d_out;

  // workspace layout — peak 9,589,760 bytes (~9.15 MB)
  float* ws   = (float*)d_ws;
  float* q    = ws;                 // 1024
  float* qwk  = ws + 1024;          // 16384 [hh][d]
  float* qwkp = ws + 17408;         // 4096  [v][hh][k]
  float* qwkc = ws + 21504;         // 256   [v][hh]
  float* wvp  = ws + 21760;         // 262144 [v][d][k]
  float* wvc  = ws + 283904;        // 16384 [v][d]  -> ends at byte 1,201,152
  float* W2   = (float*)((char*)d_ws + 1201152);  // [1024][1024] = wo·wv, 4 MB -> ends 5,395,456
  float* wvT  = (float*)((char*)d_ws + 5395456);  // [1024][1024] wv^T, 4 MB (dead after W2)
  float* ctxb = (float*)((char*)d_ws + 5395456);  // [1024][1024] ctx chunk, 4 MB (reuses wvT)

  k_q      <<<4,  256, 0, stream>>>(cq, wq, bq, q);
  k_qwk    <<<64, 256, 0, stream>>>(q, wk, qwk);
  k_qwkpc  <<<17, 256, 0, stream>>>(qwk, proj_w, proj_b, ce, qwkp, qwkc);
  k_wvp    <<<64, 256, 0, stream>>>(wv, proj_w, proj_b, ce, bv, wvp, wvc);
  k_transpose<<<dim3(16,16), 256, 0, stream>>>(wv, wvT);
  // W2[n][dd] = sum_d wo[n][d]*wv[d][dd]
  k_gemm_cat<<<dim3(8,8), 256, 0, stream>>>(wo, wvT, nullptr, nullptr, nullptr, W2,
                                            1024, 1024, 1024, 0);
  for (int b = 0; b < 2; ++b){
    for (int lb = 0; lb < 2048; lb += 1024){
      k_fused<<<256, 256, 0, stream>>>(x, b, lb, qwkp, qwkc, wvp, wvc, ctxb);
      // out_chunk = ctx0·wo^T + pe_chunk·W2^T + bo   (K = 1024 + 1024 concatenated)
      k_gemm_cat<<<dim3(8,8), 256, 0, stream>>>(ctxb, wo, pe + (size_t)lb*D_, W2, bo,
                                                out + ((size_t)b*L_ + lb)*D_,
                                                1024, 1024, 1024, 1024);
    }
  }
}

// Round 4
// 419.416 us; speedup vs baseline: 2.6182x; 2.6182x over previous
//
#include <hip/hip_runtime.h>
#include <hip/hip_bf16.h>

using bf16 = __hip_bfloat16;
using bf16x8 = __attribute__((ext_vector_type(8))) short;
using f32x4  = __attribute__((ext_vector_type(4))) float;

__device__ inline unsigned short f2bu(float f){ bf16 h = __float2bfloat16(f); return *(unsigned short*)&h; }

constexpr int D_ = 1024, L_ = 2048;

// ---------------------------------------------------------------------------
// q[e] = bq[e] + sum_d cq[d]*wq[e,d]
__global__ __launch_bounds__(256) void k_q(const float* __restrict__ cq, const float* __restrict__ wq,
                                           const float* __restrict__ bq, float* __restrict__ q){
  int e = blockIdx.x*256 + threadIdx.x;
  const float* wr = wq + (size_t)e*D_;
  float acc = bq[e];
  for (int dd=0; dd<D_; dd+=8){
    float4 a0 = *(const float4*)(wr+dd), a1 = *(const float4*)(wr+dd+4);
    float4 c0 = *(const float4*)(cq+dd), c1 = *(const float4*)(cq+dd+4);
    acc += a0.x*c0.x + a0.y*c0.y + a0.z*c0.z + a0.w*c0.w
         + a1.x*c1.x + a1.y*c1.y + a1.z*c1.z + a1.w*c1.w;
  }
  q[e] = acc;
}

// qwk[hh][d] = sum_e q[hh*64+e]*wk[hh*64+e, d]
__global__ __launch_bounds__(256) void k_qwk(const float* __restrict__ q, const float* __restrict__ wk,
                                             float* __restrict__ qwk){
  int idx = blockIdx.x*256 + threadIdx.x;
  int hh = idx >> 10, d = idx & 1023;
  float acc = 0.f;
  for (int e=0;e<64;++e)
    acc += q[hh*64+e]*wk[(size_t)(hh*64+e)*D_ + d];
  qwk[idx] = acc;
}

// ---------------------------------------------------------------------------
// qwkp[v][hh][k] = (1/8) sum_d qwk[hh][d]*proj_w[v][d][k];  qwkc likewise vs (pb+ce)
// grid 256 = (v,hh); threads = (ds 0..15) x (k 0..15); d-split + LDS reduce
__global__ __launch_bounds__(256) void k_qwkpc2(const float* __restrict__ qwk, const float* __restrict__ proj_w,
                                                const float* __restrict__ proj_b, const float* __restrict__ ce,
                                                float* __restrict__ qwkp, float* __restrict__ qwkc){
  __shared__ float red[16][17];
  __shared__ float redc[16];
  const int v = blockIdx.x >> 4, hh = blockIdx.x & 15;
  const int ds = threadIdx.x >> 4, k = threadIdx.x & 15;
  const float* qr = qwk + hh*D_ + ds*64;
  const float* pr = proj_w + ((size_t)v*D_ + ds*64)*16 + k;
  float a0=0.f, a1=0.f;
  #pragma unroll
  for (int j=0;j<64;j+=2){ a0 += qr[j]*pr[j*16]; a1 += qr[j+1]*pr[(j+1)*16]; }
  red[ds][k] = a0+a1;
  if (k==0){
    const float* pb = proj_b + v*D_ + ds*64;
    const float* cc = ce     + v*D_ + ds*64;
    float pc = 0.f;
    #pragma unroll
    for (int j=0;j<64;++j) pc += qr[j]*(pb[j]+cc[j]);
    redc[ds] = pc;
  }
  __syncthreads();
  if (threadIdx.x < 16){
    float s = 0.f;
    #pragma unroll
    for (int d2=0; d2<16; ++d2) s += red[d2][threadIdx.x];
    qwkp[(v*16+hh)*16 + threadIdx.x] = s*0.125f;
  } else if (threadIdx.x == 16){
    float s = 0.f;
    #pragma unroll
    for (int j=0;j<16;++j) s += redc[j];
    qwkc[v*16+hh] = s*0.125f;
  }
}

// ---------------------------------------------------------------------------
// wvp[v][d][k] = sum_dd wv[d,dd]*proj_w[v][dd][k];  wvc[v][d] = sum wv*(pb+ce) + bv
// grid 1024 = v*64 + dchunk; threads = (dl 0..15) x (k 0..15)
__global__ __launch_bounds__(256) void k_wvp2(const float* __restrict__ wv, const float* __restrict__ proj_w,
                                              const float* __restrict__ proj_b, const float* __restrict__ ce,
                                              const float* __restrict__ bv, float* __restrict__ wvp,
                                              float* __restrict__ wvc){
  const int tid = threadIdx.x;
  const int dl = tid >> 4, k = tid & 15;
  const int v = blockIdx.x >> 6;
  const int d = (blockIdx.x & 63)*16 + dl;
  const float* wr = wv + (size_t)d*D_;
  const float* pr = proj_w + (size_t)v*D_*16 + k;
  float a0=0.f,a1=0.f,a2=0.f,a3=0.f;
  for (int dd=0; dd<D_; dd+=4){
    a0 += wr[dd+0]*pr[(dd+0)*16];
    a1 += wr[dd+1]*pr[(dd+1)*16];
    a2 += wr[dd+2]*pr[(dd+2)*16];
    a3 += wr[dd+3]*pr[(dd+3)*16];
  }
  wvp[((size_t)v*D_ + d)*16 + k] = (a0+a1)+(a2+a3);
  // wvc partial over dd ≡ k (mod 16), then shuffle-reduce across k
  float pc = 0.f;
  #pragma unroll 4
  for (int j=0; j<64; ++j){
    int dd = j*16 + k;
    pc += wr[dd]*(proj_b[v*D_+dd] + ce[v*D_+dd]);
  }
  #pragma unroll
  for (int m=8; m>=1; m>>=1) pc += __shfl_xor(pc, m, 16);
  if (k==0) wvc[v*D_ + d] = pc + bv[d];
}

// ---------------------------------------------------------------------------
// fp32 -> bf16 bulk convert (4 elems/thread)
__global__ __launch_bounds__(256) void k_cvt(const float* __restrict__ in, unsigned short* __restrict__ outp){
  int i = blockIdx.x*256 + threadIdx.x;
  float4 v = *(const float4*)(in + (size_t)4*i);
  *(ushort4*)(outp + (size_t)4*i) = make_ushort4(f2bu(v.x), f2bu(v.y), f2bu(v.z), f2bu(v.w));
}

// transpose + convert: outp[dd][d] = bf16(in[d][dd])
__global__ __launch_bounds__(256) void k_tc(const float* __restrict__ in, unsigned short* __restrict__ outp){
  __shared__ float t[64][68];
  const int tid = threadIdx.x;
  const int r = tid >> 2, c0 = (tid & 3)*16;
  const int d0 = blockIdx.y*64, dd0 = blockIdx.x*64;
  #pragma unroll
  for (int j=0;j<4;++j){
    float4 v = *(const float4*)(in + (size_t)(d0+r)*D_ + dd0 + c0 + 4*j);
    t[r][c0+4*j+0] = v.x; t[r][c0+4*j+1] = v.y; t[r][c0+4*j+2] = v.z; t[r][c0+4*j+3] = v.w;
  }
  __syncthreads();
  #pragma unroll
  for (int j=0;j<4;++j){
    ushort4 o = make_ushort4(f2bu(t[c0+4*j+0][r]), f2bu(t[c0+4*j+1][r]),
                             f2bu(t[c0+4*j+2][r]), f2bu(t[c0+4*j+3][r]));
    *(ushort4*)(outp + (size_t)(dd0+r)*D_ + d0 + c0 + 4*j) = o;
  }
}

// ---------------------------------------------------------------------------
// pure-bf16 GEMM: C[M][N] = bf16( A[M][K] * Bt[N][K]^T ), 128x128 tile, 4 waves
__global__ __launch_bounds__(256) void k_gemm_bb(const unsigned short* __restrict__ A,
                                                 const unsigned short* __restrict__ Bt,
                                                 unsigned short* __restrict__ C,
                                                 int M, int N, int K){
  __shared__ unsigned short As[128][40];
  __shared__ unsigned short Bs[128][40];
  const int tid = threadIdx.x;
  const int wave = tid >> 6, lane = tid & 63;
  const int wm = wave & 1, wn = wave >> 1;
  const int m0 = blockIdx.y*128, n0 = blockIdx.x*128;
  const int lm = lane & 15, kg = lane >> 4;
  f32x4 acc[4][4];
  #pragma unroll
  for (int mf=0;mf<4;++mf)
    #pragma unroll
    for (int nf=0;nf<4;++nf)
      acc[mf][nf] = (f32x4){0.f,0.f,0.f,0.f};
  for (int k0=0; k0<K; k0+=32){
    #pragma unroll
    for (int i=0;i<2;++i){
      int s = tid + 256*i;
      int row = s >> 2, col = (s & 3)*8;
      *(uint4*)(&As[row][col]) = *(const uint4*)(A  + (size_t)(m0+row)*K + k0 + col);
      *(uint4*)(&Bs[row][col]) = *(const uint4*)(Bt + (size_t)(n0+row)*K + k0 + col);
    }
    __syncthreads();
    bf16x8 af[4], bfr[4];
    #pragma unroll
    for (int f=0;f<4;++f){
      af[f]  = *(const bf16x8*)(&As[wm*64 + f*16 + lm][kg*8]);
      bfr[f] = *(const bf16x8*)(&Bs[wn*64 + f*16 + lm][kg*8]);
    }
    #pragma unroll
    for (int mf=0;mf<4;++mf)
      #pragma unroll
      for (int nf=0;nf<4;++nf)
        acc[mf][nf] = __builtin_amdgcn_mfma_f32_16x16x32_bf16(af[mf], bfr[nf], acc[mf][nf], 0,0,0);
    __syncthreads();
  }
  #pragma unroll
  for (int nf=0;nf<4;++nf){
    int col = n0 + wn*64 + nf*16 + lm;
    #pragma unroll
    for (int mf=0;mf<4;++mf)
      #pragma unroll
      for (int r=0;r<4;++r){
        int row = m0 + wm*64 + mf*16 + kg*4 + r;
        C[(size_t)row*N + col] = f2bu(acc[mf][nf][r]);
      }
  }
}

// ---------------------------------------------------------------------------
// concat GEMM: C[M][N] = A1(bf16)[M][K1]*B1(bf16)[N][K1]^T + A2(fp32)[M][K2]*B2(bf16)[N][K2]^T + bias
__global__ __launch_bounds__(256) void k_gemm_cat2(const unsigned short* __restrict__ A1,
                                                   const unsigned short* __restrict__ B1,
                                                   const float* __restrict__ A2,
                                                   const unsigned short* __restrict__ B2,
                                                   const float* __restrict__ bias, float* __restrict__ C,
                                                   int M, int N, int K1, int K2){
  __shared__ unsigned short As[128][40];
  __shared__ unsigned short Bs[128][40];
  const int tid = threadIdx.x;
  const int wave = tid >> 6, lane = tid & 63;
  const int wm = wave & 1, wn = wave >> 1;
  const int m0 = blockIdx.y*128, n0 = blockIdx.x*128;
  const int lm = lane & 15, kg = lane >> 4;
  f32x4 acc[4][4];
  #pragma unroll
  for (int mf=0;mf<4;++mf)
    #pragma unroll
    for (int nf=0;nf<4;++nf)
      acc[mf][nf] = (f32x4){0.f,0.f,0.f,0.f};
  const int K = K1 + K2;
  for (int k0=0; k0<K; k0+=32){
    if (k0 < K1){
      #pragma unroll
      for (int i=0;i<2;++i){
        int s = tid + 256*i;
        int row = s >> 2, col = (s & 3)*8;
        *(uint4*)(&As[row][col]) = *(const uint4*)(A1 + (size_t)(m0+row)*K1 + k0 + col);
        *(uint4*)(&Bs[row][col]) = *(const uint4*)(B1 + (size_t)(n0+row)*K1 + k0 + col);
      }
    } else {
      int kk = k0 - K1;
      #pragma unroll
      for (int i=0;i<4;++i){
        int s = tid + 256*i;
        int row = s >> 3, col = (s & 7)*4;
        float4 av = *(const float4*)(A2 + (size_t)(m0+row)*K2 + kk + col);
        *(ushort4*)(&As[row][col]) = make_ushort4(f2bu(av.x), f2bu(av.y), f2bu(av.z), f2bu(av.w));
      }
      #pragma unroll
      for (int i=0;i<2;++i){
        int s = tid + 256*i;
        int row = s >> 2, col = (s & 3)*8;
        *(uint4*)(&Bs[row][col]) = *(const uint4*)(B2 + (size_t)(n0+row)*K2 + kk + col);
      }
    }
    __syncthreads();
    bf16x8 af[4], bfr[4];
    #pragma unroll
    for (int f=0;f<4;++f){
      af[f]  = *(const bf16x8*)(&As[wm*64 + f*16 + lm][kg*8]);
      bfr[f] = *(const bf16x8*)(&Bs[wn*64 + f*16 + lm][kg*8]);
    }
    #pragma unroll
    for (int mf=0;mf<4;++mf)
      #pragma unroll
      for (int nf=0;nf<4;++nf)
        acc[mf][nf] = __builtin_amdgcn_mfma_f32_16x16x32_bf16(af[mf], bfr[nf], acc[mf][nf], 0,0,0);
    __syncthreads();
  }
  #pragma unroll
  for (int nf=0;nf<4;++nf){
    int col = n0 + wn*64 + nf*16 + lm;
    float bval = bias[col];
    #pragma unroll
    for (int mf=0;mf<4;++mf)
      #pragma unroll
      for (int r=0;r<4;++r){
        int row = m0 + wm*64 + mf*16 + kg*4 + r;
        C[(size_t)row*N + col] = acc[mf][nf][r] + bval;
      }
  }
}

// ---------------------------------------------------------------------------
// fused per-batch: patches -> scores -> softmax -> ctx0 (bf16, 2048x1024)
// grid 512 = 128 site-groups (16 sites) x 4 d-chunks (256 d)
__global__ __launch_bounds__(256) void k_fused2(const float* __restrict__ x, int bb,
                                                const float* __restrict__ qwkp, const float* __restrict__ qwkc,
                                                const float* __restrict__ wvp, const float* __restrict__ wvc,
                                                unsigned short* __restrict__ ctx){
  __shared__ float patchL[16][16][16];  // [s][v][k]
  __shared__ float attnL[16][16][16];   // [s][hh][v]
  const int tid = threadIdx.x;
  const int sg = blockIdx.x >> 2;
  const int dc = blockIdx.x & 3;
  { // phase A: load patches (thread = (s, v))
    const int s = tid >> 4, v = tid & 15;
    const int l = sg*16 + s;
    const int hi = l >> 6, wi = l & 63;
    const float* xp = x + ((size_t)((bb*16+v)*128 + hi*4)*256 + wi*4);
    #pragma unroll
    for (int pi=0; pi<4; ++pi){
      float4 r = *(const float4*)(xp + pi*256);
      patchL[s][v][pi*4+0] = r.x; patchL[s][v][pi*4+1] = r.y;
      patchL[s][v][pi*4+2] = r.z; patchL[s][v][pi*4+3] = r.w;
    }
  }
  __syncthreads();
  { // phase B: scores + softmax (thread = (s, hh))
    const int s = tid >> 4, hh = tid & 15;
    float sc[16];
    #pragma unroll
    for (int v=0; v<16; ++v){
      float a = qwkc[v*16+hh];
      const float* qp = qwkp + (v*16+hh)*16;
      #pragma unroll
      for (int k=0;k<16;++k) a += qp[k]*patchL[s][v][k];
      sc[v] = a;
    }
    float mx = sc[0];
    #pragma unroll
    for (int v=1;v<16;++v) mx = fmaxf(mx, sc[v]);
    float sum = 0.f;
    #pragma unroll
    for (int v=0;v<16;++v){ sc[v] = __expf(sc[v]-mx); sum += sc[v]; }
    float inv = 1.f/sum;
    #pragma unroll
    for (int v=0;v<16;++v) attnL[s][hh][v] = sc[v]*inv;
  }
  __syncthreads();
  // phase C: ctx0[s][d] = sum_v attn[s,hh,v]*(wvp[v,d,:]·patch[s,v,:] + wvc[v,d])
  const int d = dc*256 + tid;
  const int hh = d >> 6;
  const int l0 = sg*16;
  float acc[16];
  #pragma unroll
  for (int s=0;s<16;++s) acc[s] = 0.f;
  for (int v=0; v<16; ++v){
    const float* wp = wvp + ((size_t)v*D_ + d)*16;
    float w[16];
    #pragma unroll
    for (int k=0;k<16;++k) w[k] = wp[k];
    const float c0 = wvc[v*D_ + d];
    #pragma unroll
    for (int s=0;s<16;++s){
      float dot = c0;
      #pragma unroll
      for (int k=0;k<16;++k) dot += w[k]*patchL[s][v][k];
      acc[s] += attnL[s][hh][v]*dot;
    }
  }
  #pragma unroll
  for (int s=0;s<16;++s) ctx[(size_t)(l0+s)*D_ + d] = f2bu(acc[s]);
}

// ---------------------------------------------------------------------------
extern "C" void kernel_launch(void* const* d_in, const int* in_sizes, int n_in,
                              void* d_out, int out_size, void* d_ws, size_t ws_size,
                              hipStream_t stream){
  const float* x      = (const float*)d_in[0];
  const float* proj_w = (const float*)d_in[1];
  const float* proj_b = (const float*)d_in[2];
  const float* ce     = (const float*)d_in[3];
  const float* pe     = (const float*)d_in[4];
  const float* cq     = (const float*)d_in[5];
  const float* wq     = (const float*)d_in[6];
  const float* wk     = (const float*)d_in[7];
  const float* wv     = (const float*)d_in[8];
  const float* bq     = (const float*)d_in[9];
  // bk (d_in[10]) cancels in softmax
  const float* bv     = (const float*)d_in[11];
  const float* wo     = (const float*)d_in[12];
  const float* bo     = (const float*)d_in[13];
  float* out = (float*)d_out;

  // workspace — peak 9,589,760 B (same as R3's proven layout)
  float* ws   = (float*)d_ws;
  float* q    = ws;                 // 1024
  float* qwk  = ws + 1024;          // 16384 [hh][d]
  float* qwkp = ws + 17408;         // 4096  [v][hh][k]
  float* qwkc = ws + 21504;         // 256   [v][hh]
  float* wvp  = ws + 21760;         // 262144 [v][d][k]
  float* wvc  = ws + 283904;        // 16384 [v][d]  -> ends at byte 1,201,152
  unsigned short* wob  = (unsigned short*)((char*)d_ws + 1201152); // bf16 wo, 2 MB -> 3,298,304
  unsigned short* W2b  = (unsigned short*)((char*)d_ws + 3298304); // bf16 wo·wv, 2 MB -> 5,395,456
  unsigned short* wvTb = (unsigned short*)((char*)d_ws + 5395456); // bf16 wv^T, 2 MB (dead after W2 gemm)
  unsigned short* ctxb = (unsigned short*)((char*)d_ws + 5395456); // bf16 [2048][1024], 4 MB -> 9,589,760

  k_q      <<<4,    256, 0, stream>>>(cq, wq, bq, q);
  k_qwk    <<<64,   256, 0, stream>>>(q, wk, qwk);
  k_qwkpc2 <<<256,  256, 0, stream>>>(qwk, proj_w, proj_b, ce, qwkp, qwkc);
  k_wvp2   <<<1024, 256, 0, stream>>>(wv, proj_w, proj_b, ce, bv, wvp, wvc);
  k_cvt    <<<1024, 256, 0, stream>>>(wo, wob);
  k_tc     <<<dim3(16,16), 256, 0, stream>>>(wv, wvTb);
  // W2 = wo · wv  (A=wob, Bt=wv^T)
  k_gemm_bb<<<dim3(8,8), 256, 0, stream>>>(wob, wvTb, W2b, 1024, 1024, 1024);
  for (int b = 0; b < 2; ++b){
    k_fused2<<<512, 256, 0, stream>>>(x, b, qwkp, qwkc, wvp, wvc, ctxb);
    // out_b = ctx0·wo^T + pe·W2^T + bo   (K = 1024 bf16 + 1024 fp32-cvt)
    k_gemm_cat2<<<dim3(8,16), 256, 0, stream>>>(ctxb, wob, pe, W2b, bo,
                                                out + (size_t)b*L_*D_,
                                                2048, 1024, 1024, 1024);
  }
}